// Round 19
// baseline (258.610 us; speedup 1.0000x reference)
//
#include <hip/hip_runtime.h>
#include <hip/hip_bf16.h>
#include <math.h>

// Problem constants
constexpr int kB = 4;
constexpr int kN = 2048;
constexpr int kC = 256;
constexpr int kDFF = 1024;
constexpr int kKNN = 16;
constexpr int kDH = 64;

typedef __attribute__((ext_vector_type(8))) short short8;
typedef __attribute__((ext_vector_type(4))) short short4v;
typedef __attribute__((ext_vector_type(4))) float float4v;

__device__ __forceinline__ float gelu_erf(float x) {
    return 0.5f * x * (1.0f + erff(x * 0.70710678118654752440f));
}

// fp32 -> bf16 bits, round-to-nearest-even (bit-exact with HW conversion)
__device__ __forceinline__ short f2b(float f) {
    unsigned u = __float_as_uint(f);
    u = u + 0x7FFFu + ((u >> 16) & 1u);
    return (short)(u >> 16);
}

// bf16 bits -> fp32 (exact)
__device__ __forceinline__ float b2f(short h) {
    unsigned u = ((unsigned)(unsigned short)h) << 16;
    return __uint_as_float(u);
}

// async global->LDS, 16B per lane: LDS dest = wave-uniform base + lane*16.
__device__ __forceinline__ void gload16(const short* g, short* l) {
    __builtin_amdgcn_global_load_lds(
        (const __attribute__((address_space(1))) void*)g,
        (__attribute__((address_space(3))) void*)l, 16, 0, 0);
}

// ---------------------------------------------------------------------------
// 0) one-shot weight conversions, single launch.
// ---------------------------------------------------------------------------
__global__ __launch_bounds__(256) void cvt_all(
    const float* __restrict__ Wqkv, const float* __restrict__ Wo,
    const float* __restrict__ W1, const float* __restrict__ W2,
    const float* __restrict__ Wp, short* __restrict__ dst)
{
    const int i = (blockIdx.x * 256 + threadIdx.x) * 8;
    if (i < 786432) {
        const float* src; int off;
        if (i < 196608)      { src = Wqkv; off = i; }
        else if (i < 262144) { src = Wo;   off = i - 196608; }
        else if (i < 524288) { src = W1;   off = i - 262144; }
        else                 { src = W2;   off = i - 524288; }
        short8 v;
        #pragma unroll
        for (int j = 0; j < 8; j++) v[j] = f2b(src[off + j]);
        *(short8*)&dst[i] = v;
    } else {
        const int off = i - 786432;           // 0..65528
        short8 h, l;
        #pragma unroll
        for (int j = 0; j < 8; j++) {
            float v = Wp[off + j];
            short hh = f2b(v);
            h[j] = hh;
            l[j] = f2b(v - b2f(hh));
        }
        *(short8*)&dst[786432 + off] = h;     // Wphi
        *(short8*)&dst[851968 + off] = l;     // Wplo
    }
}

// ---------------------------------------------------------------------------
// 0c) src (b,C,N) f32 -> srcT (z,N,C) bf16 hi/lo, z = s*4+b (rows 0..16383).
// ---------------------------------------------------------------------------
__global__ __launch_bounds__(256) void transpose_cvt(
    const float* __restrict__ src1, const float* __restrict__ src2,
    short* __restrict__ hiT, short* __restrict__ loT)
{
    __shared__ float tile[32][33];
    const int z = blockIdx.z;
    const float* in = (z < 4 ? src1 : src2) + (size_t)(z & 3) * kC * kN;
    const int n0 = blockIdx.x * 32;
    const int c0 = blockIdx.y * 32;
    const int tx = threadIdx.x;   // 32
    const int ty = threadIdx.y;   // 8
    #pragma unroll
    for (int i = 0; i < 32; i += 8)
        tile[ty + i][tx] = in[(size_t)(c0 + ty + i) * kN + (n0 + tx)];
    __syncthreads();
    #pragma unroll
    for (int i = 0; i < 32; i += 8) {
        float v = tile[tx][ty + i];                 // src[c0+tx][n0+ty+i]
        short h = f2b(v);
        short l = f2b(v - b2f(h));
        size_t o = ((size_t)z * kN + (n0 + ty + i)) * kC + (c0 + tx);
        hiT[o] = h;
        loT[o] = l;
    }
}

// ---------------------------------------------------------------------------
// 1) input_proj as bf16x3 MFMA GEMM, BK=64, global_load_lds staging
//    (same swizzle pattern as 2a, verified bit-identical in R18):
//    linear [64][64] LDS x4; lane l stages row base+l/8, granule l%8,
//    sourcing global granule (l%8)^(l/8); reads use (g^(lm&7))*8.
// ---------------------------------------------------------------------------
__global__ __launch_bounds__(256) void proj_mfma(
    const short* __restrict__ Ahi, const short* __restrict__ Alo,
    const short* __restrict__ Whi, const short* __restrict__ Wlo,
    const float* __restrict__ bias, float* __restrict__ out)
{
    __shared__ __align__(128) short AsmH[64][64], AsmL[64][64];
    __shared__ __align__(128) short BsmH[64][64], BsmL[64][64];

    const int tid = threadIdx.x;
    const int n0 = blockIdx.x * 64;
    const size_t m0 = (size_t)blockIdx.y * 64;
    const int lane = tid & 63, wv = tid >> 6;
    const int lm = lane & 15, quad = lane >> 4;
    const int rl = lane >> 3, gl = lane & 7;

    float4v acc[4] = {};

    for (int k0 = 0; k0 < kC; k0 += 64) {
        #pragma unroll
        for (int i = 0; i < 2; i++) {
            const int row = wv * 16 + i * 8 + rl;   // row&7 == rl
            const size_t gA = (m0 + row) * kC + k0 + ((gl ^ rl) * 8);
            const size_t gB = (size_t)(n0 + row) * kC + k0 + ((gl ^ rl) * 8);
            gload16(&Ahi[gA], &AsmH[wv * 16 + i * 8][0]);
            gload16(&Alo[gA], &AsmL[wv * 16 + i * 8][0]);
            gload16(&Whi[gB], &BsmH[wv * 16 + i * 8][0]);
            gload16(&Wlo[gB], &BsmL[wv * 16 + i * 8][0]);
        }
        __syncthreads();

        const int sw0 = (quad ^ (lm & 7)) * 8;
        const int sw1 = ((4 + quad) ^ (lm & 7)) * 8;
        short8 ah0 = *(const short8*)&AsmH[wv * 16 + lm][sw0];
        short8 ah1 = *(const short8*)&AsmH[wv * 16 + lm][sw1];
        short8 al0 = *(const short8*)&AsmL[wv * 16 + lm][sw0];
        short8 al1 = *(const short8*)&AsmL[wv * 16 + lm][sw1];
        #pragma unroll
        for (int j4 = 0; j4 < 4; j4++) {
            short8 bh0 = *(const short8*)&BsmH[j4 * 16 + lm][sw0];
            short8 bh1 = *(const short8*)&BsmH[j4 * 16 + lm][sw1];
            short8 bl0 = *(const short8*)&BsmL[j4 * 16 + lm][sw0];
            short8 bl1 = *(const short8*)&BsmL[j4 * 16 + lm][sw1];
            acc[j4] = __builtin_amdgcn_mfma_f32_16x16x32_bf16(al0, bh0, acc[j4], 0, 0, 0);
            acc[j4] = __builtin_amdgcn_mfma_f32_16x16x32_bf16(ah0, bl0, acc[j4], 0, 0, 0);
            acc[j4] = __builtin_amdgcn_mfma_f32_16x16x32_bf16(ah0, bh0, acc[j4], 0, 0, 0);
            acc[j4] = __builtin_amdgcn_mfma_f32_16x16x32_bf16(al1, bh1, acc[j4], 0, 0, 0);
            acc[j4] = __builtin_amdgcn_mfma_f32_16x16x32_bf16(ah1, bl1, acc[j4], 0, 0, 0);
            acc[j4] = __builtin_amdgcn_mfma_f32_16x16x32_bf16(ah1, bh1, acc[j4], 0, 0, 0);
        }
        __syncthreads();
    }

    #pragma unroll
    for (int j4 = 0; j4 < 4; j4++) {
        const int n = n0 + j4 * 16 + lm;
        const float bn = bias[n];
        #pragma unroll
        for (int rg = 0; rg < 4; rg++) {
            const size_t m = m0 + wv * 16 + quad * 4 + rg;
            out[m * kC + n] = acc[j4][rg] + bn;
        }
    }
}

// ---------------------------------------------------------------------------
// 2a) MFMA GEMM, bf16, 64x64, BK=64, global_load_lds staging (R18-verified).
// ---------------------------------------------------------------------------
__global__ __launch_bounds__(256) void mfma_gemm_bf(
    const short* __restrict__ A, const short* __restrict__ W,
    const float* __restrict__ bias, const float* __restrict__ resid,
    float* __restrict__ out, short* __restrict__ outbf,
    int M, int Nout, int K, int epi)
{
    __shared__ __align__(128) short Asm[64][64];
    __shared__ __align__(128) short Bsm[64][64];

    const int tid = threadIdx.x;
    const int n0 = blockIdx.x * 64;
    const int m0 = blockIdx.y * 64;
    const int lane = tid & 63, wv = tid >> 6;
    const int lm = lane & 15, quad = lane >> 4;
    const int rl = lane >> 3, gl = lane & 7;      // staging: 8-row group decomp

    float4v acc[4] = {};

    for (int k0 = 0; k0 < K; k0 += 64) {
        #pragma unroll
        for (int i = 0; i < 2; i++) {
            const int row = wv * 16 + i * 8 + rl;   // row&7 == rl
            gload16(&A[(size_t)(m0 + row) * K + k0 + ((gl ^ rl) * 8)],
                    &Asm[wv * 16 + i * 8][0]);
            gload16(&W[(size_t)(n0 + row) * K + k0 + ((gl ^ rl) * 8)],
                    &Bsm[wv * 16 + i * 8][0]);
        }
        __syncthreads();

        const int sw0 = (quad ^ (lm & 7)) * 8;
        const int sw1 = ((4 + quad) ^ (lm & 7)) * 8;
        short8 af0 = *(const short8*)&Asm[wv * 16 + lm][sw0];
        short8 af1 = *(const short8*)&Asm[wv * 16 + lm][sw1];
        #pragma unroll
        for (int j4 = 0; j4 < 4; j4++) {
            short8 bf0 = *(const short8*)&Bsm[j4 * 16 + lm][sw0];
            short8 bf1 = *(const short8*)&Bsm[j4 * 16 + lm][sw1];
            acc[j4] = __builtin_amdgcn_mfma_f32_16x16x32_bf16(af0, bf0, acc[j4], 0, 0, 0);
            acc[j4] = __builtin_amdgcn_mfma_f32_16x16x32_bf16(af1, bf1, acc[j4], 0, 0, 0);
        }
        __syncthreads();
    }

    #pragma unroll
    for (int j4 = 0; j4 < 4; j4++) {
        const int n = n0 + j4 * 16 + lm;
        const float bn = bias[n];
        #pragma unroll
        for (int rg = 0; rg < 4; rg++) {
            const int m = m0 + wv * 16 + quad * 4 + rg;
            float v = acc[j4][rg] + bn;
            if (resid) v += resid[(size_t)m * Nout + n];
            if (epi == 1) v = gelu_erf(v);
            if (out)   out[(size_t)m * Nout + n] = v;
            if (outbf) outbf[(size_t)m * Nout + n] = f2b(v);
        }
    }
}

// ---------------------------------------------------------------------------
// 2b) merged q + kv projection, 64x64, BK=64, global_load_lds (R18-verified).
// ---------------------------------------------------------------------------
__global__ __launch_bounds__(256) void qkv_gemm(
    const short* __restrict__ x1bf, const short* __restrict__ x2bf,
    const short* __restrict__ Wqkvbf, const float* __restrict__ bqkv,
    float* __restrict__ qb, float* __restrict__ kvb)
{
    __shared__ __align__(128) short Asm[64][64];
    __shared__ __align__(128) short Bsm[64][64];

    const int n0g = blockIdx.x * 64;            // 0..704
    const int m0 = blockIdx.y * 64;
    const short* A; float* out; int Nout; int ncol0;
    if (n0g < 256) { A = x1bf; out = qb;  Nout = 256; ncol0 = n0g; }
    else           { A = x2bf; out = kvb; Nout = 512; ncol0 = n0g - 256; }

    const int tid = threadIdx.x;
    const int lane = tid & 63, wv = tid >> 6;
    const int lm = lane & 15, quad = lane >> 4;
    const int rl = lane >> 3, gl = lane & 7;

    float4v acc[4] = {};

    for (int k0 = 0; k0 < kC; k0 += 64) {
        #pragma unroll
        for (int i = 0; i < 2; i++) {
            const int row = wv * 16 + i * 8 + rl;
            gload16(&A[(size_t)(m0 + row) * kC + k0 + ((gl ^ rl) * 8)],
                    &Asm[wv * 16 + i * 8][0]);
            gload16(&Wqkvbf[(size_t)(n0g + row) * kC + k0 + ((gl ^ rl) * 8)],
                    &Bsm[wv * 16 + i * 8][0]);
        }
        __syncthreads();

        const int sw0 = (quad ^ (lm & 7)) * 8;
        const int sw1 = ((4 + quad) ^ (lm & 7)) * 8;
        short8 af0 = *(const short8*)&Asm[wv * 16 + lm][sw0];
        short8 af1 = *(const short8*)&Asm[wv * 16 + lm][sw1];
        #pragma unroll
        for (int j4 = 0; j4 < 4; j4++) {
            short8 bf0 = *(const short8*)&Bsm[j4 * 16 + lm][sw0];
            short8 bf1 = *(const short8*)&Bsm[j4 * 16 + lm][sw1];
            acc[j4] = __builtin_amdgcn_mfma_f32_16x16x32_bf16(af0, bf0, acc[j4], 0, 0, 0);
            acc[j4] = __builtin_amdgcn_mfma_f32_16x16x32_bf16(af1, bf1, acc[j4], 0, 0, 0);
        }
        __syncthreads();
    }

    #pragma unroll
    for (int j4 = 0; j4 < 4; j4++) {
        const int nc = ncol0 + j4 * 16 + lm;
        const float bn = bqkv[n0g + j4 * 16 + lm];
        #pragma unroll
        for (int rg = 0; rg < 4; rg++) {
            const int m = m0 + wv * 16 + quad * 4 + rg;
            out[(size_t)m * Nout + nc] = acc[j4][rg] + bn;
        }
    }
}

// ---------------------------------------------------------------------------
// 2c) ffn2 with fused transposed output, 64x64, BK=64, gload_lds (R18).
// ---------------------------------------------------------------------------
__global__ __launch_bounds__(256) void ffn2_gemm_tr(
    const short* __restrict__ A, const short* __restrict__ W,
    const float* __restrict__ bias, const float* __restrict__ resid,
    float* __restrict__ out)
{
    __shared__ __align__(128) short Asm[64][64];
    __shared__ __align__(128) short Bsm[64][64];
    __shared__ float T[64][65];                   // output tile, n-major

    constexpr int K = kDFF;                       // 1024
    constexpr int Nout = kC;                      // 256
    const int tid = threadIdx.x;
    const int n0 = blockIdx.x * 64;
    const int m0 = blockIdx.y * 64;
    const int lane = tid & 63, wv = tid >> 6;
    const int lm = lane & 15, quad = lane >> 4;
    const int rl = lane >> 3, gl = lane & 7;

    float4v acc[4] = {};

    for (int k0 = 0; k0 < K; k0 += 64) {
        #pragma unroll
        for (int i = 0; i < 2; i++) {
            const int row = wv * 16 + i * 8 + rl;
            gload16(&A[(size_t)(m0 + row) * K + k0 + ((gl ^ rl) * 8)],
                    &Asm[wv * 16 + i * 8][0]);
            gload16(&W[(size_t)(n0 + row) * K + k0 + ((gl ^ rl) * 8)],
                    &Bsm[wv * 16 + i * 8][0]);
        }
        __syncthreads();

        const int sw0 = (quad ^ (lm & 7)) * 8;
        const int sw1 = ((4 + quad) ^ (lm & 7)) * 8;
        short8 af0 = *(const short8*)&Asm[wv * 16 + lm][sw0];
        short8 af1 = *(const short8*)&Asm[wv * 16 + lm][sw1];
        #pragma unroll
        for (int j4 = 0; j4 < 4; j4++) {
            short8 bf0 = *(const short8*)&Bsm[j4 * 16 + lm][sw0];
            short8 bf1 = *(const short8*)&Bsm[j4 * 16 + lm][sw1];
            acc[j4] = __builtin_amdgcn_mfma_f32_16x16x32_bf16(af0, bf0, acc[j4], 0, 0, 0);
            acc[j4] = __builtin_amdgcn_mfma_f32_16x16x32_bf16(af1, bf1, acc[j4], 0, 0, 0);
        }
        __syncthreads();
    }

    // epilogue -> LDS tile T[nloc][mloc]
    #pragma unroll
    for (int j4 = 0; j4 < 4; j4++) {
        const int nloc = j4 * 16 + lm;
        const float bn = bias[n0 + nloc];
        #pragma unroll
        for (int rg = 0; rg < 4; rg++) {
            const int mloc = wv * 16 + quad * 4 + rg;
            float v = acc[j4][rg] + bn;
            v += resid[(size_t)(m0 + mloc) * Nout + (n0 + nloc)];
            T[nloc][mloc] = v;
        }
    }
    __syncthreads();

    // transposed write: out[b][n0+nloc][nb+mloc], 64B-contiguous per 4 lanes
    const int bidx = m0 >> 11;          // m0 / 2048
    const int nb = m0 & 2047;           // within-batch position
    const int nloc = tid >> 2;
    const int l4 = tid & 3;
    float* orow = out + (size_t)bidx * kC * kN + (size_t)(n0 + nloc) * kN + nb;
    #pragma unroll
    for (int i = 0; i < 4; i++) {
        const int mloc = l4 * 4 + i * 16;
        float4v v4;
        v4[0] = T[nloc][mloc];     v4[1] = T[nloc][mloc + 1];
        v4[2] = T[nloc][mloc + 2]; v4[3] = T[nloc][mloc + 3];
        *(float4v*)&orow[mloc] = v4;
    }
}

// ---------------------------------------------------------------------------
// 3) LayerNorm, wave-per-row (R14-verified): shuffle-only, 4 rows/block.
//    Rows >= wlim skip the dead f32 writeback.
// ---------------------------------------------------------------------------
__global__ __launch_bounds__(256) void ln_kernel(
    float* __restrict__ x, short* __restrict__ xbf,
    const float* __restrict__ g, const float* __restrict__ bb, int wlim)
{
    const int lane = threadIdx.x & 63;
    const size_t row = (size_t)blockIdx.x * 4 + (threadIdx.x >> 6);

    float4v v = *(const float4v*)&x[row * kC + lane * 4];
    float s = (v[0] + v[1]) + (v[2] + v[3]);
    #pragma unroll
    for (int off = 32; off; off >>= 1) s += __shfl_xor(s, off, 64);
    const float mean = s * (1.0f / kC);

    float d0 = v[0] - mean, d1 = v[1] - mean, d2 = v[2] - mean, d3 = v[3] - mean;
    float s2 = (d0 * d0 + d1 * d1) + (d2 * d2 + d3 * d3);
    #pragma unroll
    for (int off = 32; off; off >>= 1) s2 += __shfl_xor(s2, off, 64);
    const float var = s2 * (1.0f / kC);
    const float r = 1.0f / sqrtf(var + 1e-5f);

    const float4v g4 = *(const float4v*)&g[lane * 4];
    const float4v b4 = *(const float4v*)&bb[lane * 4];
    float4v o;
    o[0] = d0 * r * g4[0] + b4[0];
    o[1] = d1 * r * g4[1] + b4[1];
    o[2] = d2 * r * g4[2] + b4[2];
    o[3] = d3 * r * g4[3] + b4[3];

    if ((int)row < wlim) *(float4v*)&x[row * kC + lane * 4] = o;
    short4v ob;
    ob[0] = f2b(o[0]); ob[1] = f2b(o[1]); ob[2] = f2b(o[2]); ob[3] = f2b(o[3]);
    *(short4v*)&xbf[row * kC + lane * 4] = ob;
}

// ---------------------------------------------------------------------------
// 4) wave-per-query KNN, tournament-tree selection — R6 version verbatim
//    (empirically fastest: 53 us; R7/R8/R15 restructures all regressed).
// ---------------------------------------------------------------------------
#define KNN_RESCAN(CH, BM, BI)                                        \
    do {                                                              \
        float nb_ = 1e30f; int ni_ = kN;                              \
        _Pragma("unroll")                                             \
        for (int c8_ = 0; c8_ < 8; c8_++) {                           \
            int c_ = (CH) * 8 + c8_;                                  \
            float dd_ = (mask & (1u << c_)) ? 1e30f : cd[c_];         \
            if (dd_ < nb_) { nb_ = dd_; ni_ = c_ * 64 + lane; }       \
        }                                                             \
        BM = nb_; BI = ni_;                                           \
    } while (0)

__global__ __launch_bounds__(512) void knn_kernel(
    const float* __restrict__ pos,
    const float* __restrict__ Wr1, const float* __restrict__ br1,
    const float* __restrict__ Wr2, const float* __restrict__ br2,
    int* __restrict__ idx_out, float* __restrict__ bias_out)
{
    __shared__ float px[kN], py[kN], pz[kN];
    __shared__ int selS[8][kKNN];

    const int b = blockIdx.y;
    const int t = threadIdx.x;
    const int lane = t & 63, wv = t >> 6;
    const int n = blockIdx.x * 8 + wv;

    const float* pb = pos + (size_t)b * 3 * kN;
    for (int m = t; m < kN; m += 512) {
        px[m] = pb[m]; py[m] = pb[kN + m]; pz[m] = pb[2 * kN + m];
    }
    __syncthreads();

    const float qx = px[n], qy = py[n], qz = pz[n];
    const float qsq = __fadd_rn(__fadd_rn(__fmul_rn(qx, qx), __fmul_rn(qy, qy)),
                                __fmul_rn(qz, qz));

    float cd[32];
    float bm0 = 1e30f, bm1 = 1e30f, bm2 = 1e30f, bm3 = 1e30f;
    int bi0 = kN, bi1 = kN, bi2 = kN, bi3 = kN;
    #pragma unroll
    for (int c8 = 0; c8 < 8; c8++) {
        {
            const int c = c8, m = c * 64 + lane;
            float ax = px[m], ay = py[m], az = pz[m];
            float asq = __fadd_rn(__fadd_rn(__fmul_rn(ax, ax), __fmul_rn(ay, ay)), __fmul_rn(az, az));
            float dot = __fadd_rn(__fadd_rn(__fmul_rn(qx, ax), __fmul_rn(qy, ay)), __fmul_rn(qz, az));
            float d = __fsub_rn(__fadd_rn(qsq, asq), __fmul_rn(2.0f, dot));
            cd[c] = d;
            if (d < bm0) { bm0 = d; bi0 = m; }
        }
        {
            const int c = c8 + 8, m = c * 64 + lane;
            float ax = px[m], ay = py[m], az = pz[m];
            float asq = __fadd_rn(__fadd_rn(__fmul_rn(ax, ax), __fmul_rn(ay, ay)), __fmul_rn(az, az));
            float dot = __fadd_rn(__fadd_rn(__fmul_rn(qx, ax), __fmul_rn(qy, ay)), __fmul_rn(qz, az));
            float d = __fsub_rn(__fadd_rn(qsq, asq), __fmul_rn(2.0f, dot));
            cd[c] = d;
            if (d < bm1) { bm1 = d; bi1 = m; }
        }
        {
            const int c = c8 + 16, m = c * 64 + lane;
            float ax = px[m], ay = py[m], az = pz[m];
            float asq = __fadd_rn(__fadd_rn(__fmul_rn(ax, ax), __fmul_rn(ay, ay)), __fmul_rn(az, az));
            float dot = __fadd_rn(__fadd_rn(__fmul_rn(qx, ax), __fmul_rn(qy, ay)), __fmul_rn(qz, az));
            float d = __fsub_rn(__fadd_rn(qsq, asq), __fmul_rn(2.0f, dot));
            cd[c] = d;
            if (d < bm2) { bm2 = d; bi2 = m; }
        }
        {
            const int c = c8 + 24, m = c * 64 + lane;
            float ax = px[m], ay = py[m], az = pz[m];
            float asq = __fadd_rn(__fadd_rn(__fmul_rn(ax, ax), __fmul_rn(ay, ay)), __fmul_rn(az, az));
            float dot = __fadd_rn(__fadd_rn(__fmul_rn(qx, ax), __fmul_rn(qy, ay)), __fmul_rn(qz, az));
            float d = __fsub_rn(__fadd_rn(qsq, asq), __fmul_rn(2.0f, dot));
            cd[c] = d;
            if (d < bm3) { bm3 = d; bi3 = m; }
        }
    }

    unsigned mask = 0;
    for (int r = 0; r < kKNN; r++) {
        float best = bm0; int bid = bi0;
        if (bm1 < best) { best = bm1; bid = bi1; }
        if (bm2 < best) { best = bm2; bid = bi2; }
        if (bm3 < best) { best = bm3; bid = bi3; }

        #pragma unroll
        for (int off = 1; off < 64; off <<= 1) {
            float od = __shfl_xor(best, off, 64);
            int   oi = __shfl_xor(bid, off, 64);
            if (od < best || (od == best && oi < bid)) { best = od; bid = oi; }
        }
        if (lane == 0) selS[wv][r] = bid;
        if ((bid & 63) == lane) mask |= 1u << (bid >> 6);

        if (r < kKNN - 1) {
            const int sch = __builtin_amdgcn_readfirstlane(bid >> 9);
            switch (sch) {
                case 0:  KNN_RESCAN(0, bm0, bi0); break;
                case 1:  KNN_RESCAN(1, bm1, bi1); break;
                case 2:  KNN_RESCAN(2, bm2, bi2); break;
                default: KNN_RESCAN(3, bm3, bi3); break;
            }
        }
    }

    const int k = lane >> 2;
    const int part = lane & 3;
    const int m = selS[wv][k];
    const float rx = qx - px[m], ry = qy - py[m], rz = qz - pz[m];
    float partial = 0.0f;
    #pragma unroll
    for (int jj = 0; jj < 16; jj++) {
        int o = part * 16 + jj;
        float h = rx * Wr1[o * 3 + 0] + ry * Wr1[o * 3 + 1] +
                  rz * Wr1[o * 3 + 2] + br1[o];
        partial += gelu_erf(h) * Wr2[o];
    }
    partial += __shfl_xor(partial, 1, 64);
    partial += __shfl_xor(partial, 2, 64);
    if (part == 0) {
        size_t o = ((size_t)b * kN + n) * kKNN + k;
        idx_out[o] = m;
        bias_out[o] = partial + br2[0];
    }
}

// ---------------------------------------------------------------------------
// 5) sparse attention, wave-parallel QK (R17-verified).
// ---------------------------------------------------------------------------
__global__ __launch_bounds__(256) void attn_kernel(
    const float* __restrict__ q, const float* __restrict__ kv,
    const int* __restrict__ idx, const float* __restrict__ bias,
    short* __restrict__ obf)
{
    const int n = blockIdx.x;
    const int b = blockIdx.y;
    const int t = threadIdx.x;
    const int h = t >> 6;
    const int lane = t & 63;

    const size_t row = (size_t)b * kN + n;

    __shared__ int   sidx[kKNN];
    __shared__ float sb[kKNN];
    if (t < kKNN) { sidx[t] = idx[row * kKNN + t]; sb[t] = bias[row * kKNN + t]; }
    __syncthreads();

    // QK: group (j = lane>>2) x chunk (part = lane&3, dims part*16..+15)
    const int j = lane >> 2;
    const int part = lane & 3;
    const size_t krj = (size_t)b * kN + sidx[j];
    const float4v* q4 = (const float4v*)&q[row * kC + h * kDH + part * 16];
    const float4v* k4 = (const float4v*)&kv[krj * 512 + h * kDH + part * 16];
    float partial = 0.0f;
    #pragma unroll
    for (int e = 0; e < 4; e++) {
        float4v qa = q4[e], ka = k4[e];
        partial += qa[0] * ka[0] + qa[1] * ka[1] + qa[2] * ka[2] + qa[3] * ka[3];
    }
    partial += __shfl_xor(partial, 1, 64);
    partial += __shfl_xor(partial, 2, 64);
    const float scj = partial * 0.125f + sb[j];

    // broadcast all 16 scores to every lane (independent shuffles)
    float sc[kKNN];
    #pragma unroll
    for (int jj = 0; jj < kKNN; jj++) sc[jj] = __shfl(scj, jj * 4, 64);

    float mx = sc[0];
    #pragma unroll
    for (int jj = 1; jj < kKNN; jj++) mx = fmaxf(mx, sc[jj]);
    float den = 0.0f;
    #pragma unroll
    for (int jj = 0; jj < kKNN; jj++) { sc[jj] = expf(sc[jj] - mx); den += sc[jj]; }
    const float inv = 1.0f / den;

    // PV: lane = d (unchanged expressions and j-order)
    const int d = lane;
    float o = 0.0f;
    #pragma unroll
    for (int jj = 0; jj < kKNN; jj++) {
        size_t kr = (size_t)b * kN + sidx[jj];
        o += sc[jj] * inv * kv[kr * 512 + kC + h * kDH + d];
    }
    obf[row * kC + h * kDH + d] = f2b(o);
}

// ---------------------------------------------------------------------------
extern "C" void kernel_launch(void* const* d_in, const int* in_sizes, int n_in,
                              void* d_out, int out_size, void* d_ws, size_t ws_size,
                              hipStream_t stream)
{
    const float* src1 = (const float*)d_in[0];
    const float* src2 = (const float*)d_in[1];
    const float* pos  = (const float*)d_in[2];
    const float* Wp   = (const float*)d_in[3];
    const float* bp   = (const float*)d_in[4];
    const float* Wr1  = (const float*)d_in[5];
    const float* br1  = (const float*)d_in[6];
    const float* Wr2  = (const float*)d_in[7];
    const float* br2  = (const float*)d_in[8];
    const float* Wqkv = (const float*)d_in[9];
    const float* bqkv = (const float*)d_in[10];
    const float* Wo   = (const float*)d_in[11];
    const float* bo   = (const float*)d_in[12];
    const float* g13  = (const float*)d_in[13];
    const float* b13  = (const float*)d_in[14];
    const float* g12  = (const float*)d_in[15];
    const float* b12  = (const float*)d_in[16];
    const float* W1   = (const float*)d_in[17];
    const float* b1   = (const float*)d_in[18];
    const float* W2   = (const float*)d_in[19];
    const float* b2   = (const float*)d_in[20];
    float* out = (float*)d_out;                      // fp32 output (b,c,n)

    const size_t S = (size_t)kB * kN * kC;  // 2,097,152 floats
    float* ws = (float*)d_ws;
    // f32 buffers
    float* x1  = ws;             // proj s1 out; LN13 in place; resid for out-proj
    float* s2  = ws + S;         // proj s2 out (contiguous after x1)
    float* qb  = ws + 2 * S;     // q f32; yb aliases after attn
    float* kvb = ws + 3 * S;     // fused k|v f32, row stride 512 (2S); hbf aliases
    float* yb  = ws + 2 * S;     // alias qb (dead after attn)
    // bf16x2 staging for proj (dead after proj_mfma; alias qb/kvb region)
    short* srcThi = (short*)(ws + 2 * S);            // 16384x256 shorts = [2S,3S)
    short* srcTlo = (short*)(ws + 3 * S);            // 16384x256 shorts = [3S,4S)
    // bf16 buffers (as shorts)
    short* x1bf = (short*)(ws + 5 * S);              // S shorts  [5S, 5.5S)
    short* x2bf = (short*)(ws + 5 * S) + S;          // S shorts  [5.5S, 6S)
    short* ybf  = (short*)(ws + 6 * S);              // S shorts  [6S, 6.5S)
    short* obf  = (short*)(ws + 6 * S) + S;          // S shorts  [6.5S, 7S)
    short* hbf  = (short*)(ws + 3 * S);              // alias kvb: 4S shorts (M x DFF)
    // knn outputs
    int*   idxb  = (int*)(ws + 7 * S);
    float* biasb = ws + 7 * S + (size_t)kB * kN * kKNN;
    // bf16 weights (contiguous): [qkv][o][w1][w2][wp_hi][wp_lo]
    short* wbf    = (short*)(ws + 7 * S + 2 * (size_t)kB * kN * kKNN);
    short* Wqkvbf = wbf;                  // 196608 shorts
    short* Wobf   = wbf + 196608;         // 65536
    short* W1bf   = wbf + 262144;         // 262144
    short* W2bf   = wbf + 524288;         // 262144
    short* Wphi   = wbf + 786432;         // 65536
    short* Wplo   = wbf + 851968;         // 65536

    const int M = kB * kN;  // 8192

    // 0) all weight conversions in one launch
    cvt_all<<<416, 256, 0, stream>>>(Wqkv, Wo, W1, W2, Wp, wbf);

    // 1) input projection: transpose+split src, then bf16x3 MFMA GEMM (BK=64)
    transpose_cvt<<<dim3(kN / 32, kC / 32, 8), dim3(32, 8), 0, stream>>>(
        src1, src2, srcThi, srcTlo);
    proj_mfma<<<dim3(kC / 64, 2 * M / 64), 256, 0, stream>>>(
        srcThi, srcTlo, Wphi, Wplo, bp, x1);   // writes x1 then s2 (contiguous)

    // 2) LN13: 16384 rows, wave-per-row; f32 writeback only for x1 half
    ln_kernel<<<2 * M / 4, 256, 0, stream>>>(x1, x1bf, g13, b13, M);

    // 3) KNN + rel-pos bias (R6 config: 8 queries/block, 512 threads)
    knn_kernel<<<dim3(kN / 8, kB), 512, 0, stream>>>(pos, Wr1, br1, Wr2, br2, idxb, biasb);

    // 4) merged q + kv projection (64x64 tiles, BK=64, gload_lds)
    qkv_gemm<<<dim3(12, M / 64), 256, 0, stream>>>(x1bf, x2bf, Wqkvbf, bqkv, qb, kvb);

    // 5) sparse attention (wave-parallel QK, bf16 out)
    attn_kernel<<<dim3(kN, kB), 256, 0, stream>>>(qb, kvb, idxb, biasb, obf);

    // 6) out-proj + residual(x1), then LN12
    mfma_gemm_bf<<<dim3(kC / 64, M / 64), 256, 0, stream>>>(
        obf, Wobf, bo, x1, yb, nullptr, M, kC, kC, 0);
    ln_kernel<<<M / 4, 256, 0, stream>>>(yb, ybf, g12, b12, M);

    // 7) FFN: ffn1 bf16-only out; ffn2 fused transposed write to final out
    mfma_gemm_bf<<<dim3(kDFF / 64, M / 64), 256, 0, stream>>>(
        ybf, W1bf, b1, nullptr, nullptr, hbf, M, kDFF, kC, 1);
    ffn2_gemm_tr<<<dim3(kC / 64, M / 64), 256, 0, stream>>>(
        hbf, W2bf, b2, yb, out);
}

// Round 20
// 254.135 us; speedup vs baseline: 1.0176x; 1.0176x over previous
//
#include <hip/hip_runtime.h>
#include <hip/hip_bf16.h>
#include <math.h>

// Problem constants
constexpr int kB = 4;
constexpr int kN = 2048;
constexpr int kC = 256;
constexpr int kDFF = 1024;
constexpr int kKNN = 16;
constexpr int kDH = 64;

typedef __attribute__((ext_vector_type(8))) short short8;
typedef __attribute__((ext_vector_type(4))) short short4v;
typedef __attribute__((ext_vector_type(4))) float float4v;

__device__ __forceinline__ float gelu_erf(float x) {
    return 0.5f * x * (1.0f + erff(x * 0.70710678118654752440f));
}

// fp32 -> bf16 bits, round-to-nearest-even (bit-exact with HW conversion)
__device__ __forceinline__ short f2b(float f) {
    unsigned u = __float_as_uint(f);
    u = u + 0x7FFFu + ((u >> 16) & 1u);
    return (short)(u >> 16);
}

// bf16 bits -> fp32 (exact)
__device__ __forceinline__ float b2f(short h) {
    unsigned u = ((unsigned)(unsigned short)h) << 16;
    return __uint_as_float(u);
}

// async global->LDS, 16B per lane: LDS dest = wave-uniform base + lane*16.
__device__ __forceinline__ void gload16(const short* g, short* l) {
    __builtin_amdgcn_global_load_lds(
        (const __attribute__((address_space(1))) void*)g,
        (__attribute__((address_space(3))) void*)l, 16, 0, 0);
}

// ---------------------------------------------------------------------------
// 0) one-shot weight conversions, single launch.
// ---------------------------------------------------------------------------
__global__ __launch_bounds__(256) void cvt_all(
    const float* __restrict__ Wqkv, const float* __restrict__ Wo,
    const float* __restrict__ W1, const float* __restrict__ W2,
    const float* __restrict__ Wp, short* __restrict__ dst)
{
    const int i = (blockIdx.x * 256 + threadIdx.x) * 8;
    if (i < 786432) {
        const float* src; int off;
        if (i < 196608)      { src = Wqkv; off = i; }
        else if (i < 262144) { src = Wo;   off = i - 196608; }
        else if (i < 524288) { src = W1;   off = i - 262144; }
        else                 { src = W2;   off = i - 524288; }
        short8 v;
        #pragma unroll
        for (int j = 0; j < 8; j++) v[j] = f2b(src[off + j]);
        *(short8*)&dst[i] = v;
    } else {
        const int off = i - 786432;           // 0..65528
        short8 h, l;
        #pragma unroll
        for (int j = 0; j < 8; j++) {
            float v = Wp[off + j];
            short hh = f2b(v);
            h[j] = hh;
            l[j] = f2b(v - b2f(hh));
        }
        *(short8*)&dst[786432 + off] = h;     // Wphi
        *(short8*)&dst[851968 + off] = l;     // Wplo
    }
}

// ---------------------------------------------------------------------------
// 0c) src (b,C,N) f32 -> srcT (z,N,C) bf16 hi/lo, z = s*4+b (rows 0..16383).
// ---------------------------------------------------------------------------
__global__ __launch_bounds__(256) void transpose_cvt(
    const float* __restrict__ src1, const float* __restrict__ src2,
    short* __restrict__ hiT, short* __restrict__ loT)
{
    __shared__ float tile[32][33];
    const int z = blockIdx.z;
    const float* in = (z < 4 ? src1 : src2) + (size_t)(z & 3) * kC * kN;
    const int n0 = blockIdx.x * 32;
    const int c0 = blockIdx.y * 32;
    const int tx = threadIdx.x;   // 32
    const int ty = threadIdx.y;   // 8
    #pragma unroll
    for (int i = 0; i < 32; i += 8)
        tile[ty + i][tx] = in[(size_t)(c0 + ty + i) * kN + (n0 + tx)];
    __syncthreads();
    #pragma unroll
    for (int i = 0; i < 32; i += 8) {
        float v = tile[tx][ty + i];                 // src[c0+tx][n0+ty+i]
        short h = f2b(v);
        short l = f2b(v - b2f(h));
        size_t o = ((size_t)z * kN + (n0 + ty + i)) * kC + (c0 + tx);
        hiT[o] = h;
        loT[o] = l;
    }
}

// ---------------------------------------------------------------------------
// 1) input_proj as bf16x3 MFMA GEMM, BK=64, reg-staged (R16-verified; the
//    R19 gload_lds port of this 4-buffer kernel regressed — 8 gloads/lane
//    per K-step drains too deep a vmcnt queue at the barrier).
// ---------------------------------------------------------------------------
__global__ __launch_bounds__(256) void proj_mfma(
    const short* __restrict__ Ahi, const short* __restrict__ Alo,
    const short* __restrict__ Whi, const short* __restrict__ Wlo,
    const float* __restrict__ bias, float* __restrict__ out)
{
    __shared__ __align__(16) short AsmH[64][72], AsmL[64][72];
    __shared__ __align__(16) short BsmH[64][72], BsmL[64][72];

    const int tid = threadIdx.x;
    const int n0 = blockIdx.x * 64;
    const size_t m0 = (size_t)blockIdx.y * 64;
    const int lane = tid & 63, wv = tid >> 6;
    const int lm = lane & 15, quad = lane >> 4;
    const int r = tid >> 2, q = tid & 3;

    float4v acc[4] = {};

    for (int k0 = 0; k0 < kC; k0 += 64) {
        const short* ahp = &Ahi[(m0 + r) * kC + k0 + q * 16];
        *(short8*)&AsmH[r][q * 16]     = *(const short8*)ahp;
        *(short8*)&AsmH[r][q * 16 + 8] = *(const short8*)(ahp + 8);
        const short* alp = &Alo[(m0 + r) * kC + k0 + q * 16];
        *(short8*)&AsmL[r][q * 16]     = *(const short8*)alp;
        *(short8*)&AsmL[r][q * 16 + 8] = *(const short8*)(alp + 8);
        const short* bhp = &Whi[(size_t)(n0 + r) * kC + k0 + q * 16];
        *(short8*)&BsmH[r][q * 16]     = *(const short8*)bhp;
        *(short8*)&BsmH[r][q * 16 + 8] = *(const short8*)(bhp + 8);
        const short* blp = &Wlo[(size_t)(n0 + r) * kC + k0 + q * 16];
        *(short8*)&BsmL[r][q * 16]     = *(const short8*)blp;
        *(short8*)&BsmL[r][q * 16 + 8] = *(const short8*)(blp + 8);
        __syncthreads();

        short8 ah0 = *(const short8*)&AsmH[wv * 16 + lm][quad * 8];
        short8 ah1 = *(const short8*)&AsmH[wv * 16 + lm][32 + quad * 8];
        short8 al0 = *(const short8*)&AsmL[wv * 16 + lm][quad * 8];
        short8 al1 = *(const short8*)&AsmL[wv * 16 + lm][32 + quad * 8];
        #pragma unroll
        for (int j4 = 0; j4 < 4; j4++) {
            short8 bh0 = *(const short8*)&BsmH[j4 * 16 + lm][quad * 8];
            short8 bh1 = *(const short8*)&BsmH[j4 * 16 + lm][32 + quad * 8];
            short8 bl0 = *(const short8*)&BsmL[j4 * 16 + lm][quad * 8];
            short8 bl1 = *(const short8*)&BsmL[j4 * 16 + lm][32 + quad * 8];
            acc[j4] = __builtin_amdgcn_mfma_f32_16x16x32_bf16(al0, bh0, acc[j4], 0, 0, 0);
            acc[j4] = __builtin_amdgcn_mfma_f32_16x16x32_bf16(ah0, bl0, acc[j4], 0, 0, 0);
            acc[j4] = __builtin_amdgcn_mfma_f32_16x16x32_bf16(ah0, bh0, acc[j4], 0, 0, 0);
            acc[j4] = __builtin_amdgcn_mfma_f32_16x16x32_bf16(al1, bh1, acc[j4], 0, 0, 0);
            acc[j4] = __builtin_amdgcn_mfma_f32_16x16x32_bf16(ah1, bl1, acc[j4], 0, 0, 0);
            acc[j4] = __builtin_amdgcn_mfma_f32_16x16x32_bf16(ah1, bh1, acc[j4], 0, 0, 0);
        }
        __syncthreads();
    }

    #pragma unroll
    for (int j4 = 0; j4 < 4; j4++) {
        const int n = n0 + j4 * 16 + lm;
        const float bn = bias[n];
        #pragma unroll
        for (int rg = 0; rg < 4; rg++) {
            const size_t m = m0 + wv * 16 + quad * 4 + rg;
            out[m * kC + n] = acc[j4][rg] + bn;
        }
    }
}

// ---------------------------------------------------------------------------
// 2a) MFMA GEMM, bf16, 64x64, BK=64, global_load_lds staging (R18-verified).
// ---------------------------------------------------------------------------
__global__ __launch_bounds__(256) void mfma_gemm_bf(
    const short* __restrict__ A, const short* __restrict__ W,
    const float* __restrict__ bias, const float* __restrict__ resid,
    float* __restrict__ out, short* __restrict__ outbf,
    int M, int Nout, int K, int epi)
{
    __shared__ __align__(128) short Asm[64][64];
    __shared__ __align__(128) short Bsm[64][64];

    const int tid = threadIdx.x;
    const int n0 = blockIdx.x * 64;
    const int m0 = blockIdx.y * 64;
    const int lane = tid & 63, wv = tid >> 6;
    const int lm = lane & 15, quad = lane >> 4;
    const int rl = lane >> 3, gl = lane & 7;      // staging: 8-row group decomp

    float4v acc[4] = {};

    for (int k0 = 0; k0 < K; k0 += 64) {
        #pragma unroll
        for (int i = 0; i < 2; i++) {
            const int row = wv * 16 + i * 8 + rl;   // row&7 == rl
            gload16(&A[(size_t)(m0 + row) * K + k0 + ((gl ^ rl) * 8)],
                    &Asm[wv * 16 + i * 8][0]);
            gload16(&W[(size_t)(n0 + row) * K + k0 + ((gl ^ rl) * 8)],
                    &Bsm[wv * 16 + i * 8][0]);
        }
        __syncthreads();

        const int sw0 = (quad ^ (lm & 7)) * 8;
        const int sw1 = ((4 + quad) ^ (lm & 7)) * 8;
        short8 af0 = *(const short8*)&Asm[wv * 16 + lm][sw0];
        short8 af1 = *(const short8*)&Asm[wv * 16 + lm][sw1];
        #pragma unroll
        for (int j4 = 0; j4 < 4; j4++) {
            short8 bf0 = *(const short8*)&Bsm[j4 * 16 + lm][sw0];
            short8 bf1 = *(const short8*)&Bsm[j4 * 16 + lm][sw1];
            acc[j4] = __builtin_amdgcn_mfma_f32_16x16x32_bf16(af0, bf0, acc[j4], 0, 0, 0);
            acc[j4] = __builtin_amdgcn_mfma_f32_16x16x32_bf16(af1, bf1, acc[j4], 0, 0, 0);
        }
        __syncthreads();
    }

    #pragma unroll
    for (int j4 = 0; j4 < 4; j4++) {
        const int n = n0 + j4 * 16 + lm;
        const float bn = bias[n];
        #pragma unroll
        for (int rg = 0; rg < 4; rg++) {
            const int m = m0 + wv * 16 + quad * 4 + rg;
            float v = acc[j4][rg] + bn;
            if (resid) v += resid[(size_t)m * Nout + n];
            if (epi == 1) v = gelu_erf(v);
            if (out)   out[(size_t)m * Nout + n] = v;
            if (outbf) outbf[(size_t)m * Nout + n] = f2b(v);
        }
    }
}

// ---------------------------------------------------------------------------
// 2b) merged q + kv projection, 64x64, BK=64, global_load_lds (R18-verified).
// ---------------------------------------------------------------------------
__global__ __launch_bounds__(256) void qkv_gemm(
    const short* __restrict__ x1bf, const short* __restrict__ x2bf,
    const short* __restrict__ Wqkvbf, const float* __restrict__ bqkv,
    float* __restrict__ qb, float* __restrict__ kvb)
{
    __shared__ __align__(128) short Asm[64][64];
    __shared__ __align__(128) short Bsm[64][64];

    const int n0g = blockIdx.x * 64;            // 0..704
    const int m0 = blockIdx.y * 64;
    const short* A; float* out; int Nout; int ncol0;
    if (n0g < 256) { A = x1bf; out = qb;  Nout = 256; ncol0 = n0g; }
    else           { A = x2bf; out = kvb; Nout = 512; ncol0 = n0g - 256; }

    const int tid = threadIdx.x;
    const int lane = tid & 63, wv = tid >> 6;
    const int lm = lane & 15, quad = lane >> 4;
    const int rl = lane >> 3, gl = lane & 7;

    float4v acc[4] = {};

    for (int k0 = 0; k0 < kC; k0 += 64) {
        #pragma unroll
        for (int i = 0; i < 2; i++) {
            const int row = wv * 16 + i * 8 + rl;
            gload16(&A[(size_t)(m0 + row) * kC + k0 + ((gl ^ rl) * 8)],
                    &Asm[wv * 16 + i * 8][0]);
            gload16(&Wqkvbf[(size_t)(n0g + row) * kC + k0 + ((gl ^ rl) * 8)],
                    &Bsm[wv * 16 + i * 8][0]);
        }
        __syncthreads();

        const int sw0 = (quad ^ (lm & 7)) * 8;
        const int sw1 = ((4 + quad) ^ (lm & 7)) * 8;
        short8 af0 = *(const short8*)&Asm[wv * 16 + lm][sw0];
        short8 af1 = *(const short8*)&Asm[wv * 16 + lm][sw1];
        #pragma unroll
        for (int j4 = 0; j4 < 4; j4++) {
            short8 bf0 = *(const short8*)&Bsm[j4 * 16 + lm][sw0];
            short8 bf1 = *(const short8*)&Bsm[j4 * 16 + lm][sw1];
            acc[j4] = __builtin_amdgcn_mfma_f32_16x16x32_bf16(af0, bf0, acc[j4], 0, 0, 0);
            acc[j4] = __builtin_amdgcn_mfma_f32_16x16x32_bf16(af1, bf1, acc[j4], 0, 0, 0);
        }
        __syncthreads();
    }

    #pragma unroll
    for (int j4 = 0; j4 < 4; j4++) {
        const int nc = ncol0 + j4 * 16 + lm;
        const float bn = bqkv[n0g + j4 * 16 + lm];
        #pragma unroll
        for (int rg = 0; rg < 4; rg++) {
            const int m = m0 + wv * 16 + quad * 4 + rg;
            out[(size_t)m * Nout + nc] = acc[j4][rg] + bn;
        }
    }
}

// ---------------------------------------------------------------------------
// 2c) ffn2 with fused transposed output, 64x64, BK=64, gload_lds (R18).
// ---------------------------------------------------------------------------
__global__ __launch_bounds__(256) void ffn2_gemm_tr(
    const short* __restrict__ A, const short* __restrict__ W,
    const float* __restrict__ bias, const float* __restrict__ resid,
    float* __restrict__ out)
{
    __shared__ __align__(128) short Asm[64][64];
    __shared__ __align__(128) short Bsm[64][64];
    __shared__ float T[64][65];                   // output tile, n-major

    constexpr int K = kDFF;                       // 1024
    constexpr int Nout = kC;                      // 256
    const int tid = threadIdx.x;
    const int n0 = blockIdx.x * 64;
    const int m0 = blockIdx.y * 64;
    const int lane = tid & 63, wv = tid >> 6;
    const int lm = lane & 15, quad = lane >> 4;
    const int rl = lane >> 3, gl = lane & 7;

    float4v acc[4] = {};

    for (int k0 = 0; k0 < K; k0 += 64) {
        #pragma unroll
        for (int i = 0; i < 2; i++) {
            const int row = wv * 16 + i * 8 + rl;
            gload16(&A[(size_t)(m0 + row) * K + k0 + ((gl ^ rl) * 8)],
                    &Asm[wv * 16 + i * 8][0]);
            gload16(&W[(size_t)(n0 + row) * K + k0 + ((gl ^ rl) * 8)],
                    &Bsm[wv * 16 + i * 8][0]);
        }
        __syncthreads();

        const int sw0 = (quad ^ (lm & 7)) * 8;
        const int sw1 = ((4 + quad) ^ (lm & 7)) * 8;
        short8 af0 = *(const short8*)&Asm[wv * 16 + lm][sw0];
        short8 af1 = *(const short8*)&Asm[wv * 16 + lm][sw1];
        #pragma unroll
        for (int j4 = 0; j4 < 4; j4++) {
            short8 bf0 = *(const short8*)&Bsm[j4 * 16 + lm][sw0];
            short8 bf1 = *(const short8*)&Bsm[j4 * 16 + lm][sw1];
            acc[j4] = __builtin_amdgcn_mfma_f32_16x16x32_bf16(af0, bf0, acc[j4], 0, 0, 0);
            acc[j4] = __builtin_amdgcn_mfma_f32_16x16x32_bf16(af1, bf1, acc[j4], 0, 0, 0);
        }
        __syncthreads();
    }

    // epilogue -> LDS tile T[nloc][mloc]
    #pragma unroll
    for (int j4 = 0; j4 < 4; j4++) {
        const int nloc = j4 * 16 + lm;
        const float bn = bias[n0 + nloc];
        #pragma unroll
        for (int rg = 0; rg < 4; rg++) {
            const int mloc = wv * 16 + quad * 4 + rg;
            float v = acc[j4][rg] + bn;
            v += resid[(size_t)(m0 + mloc) * Nout + (n0 + nloc)];
            T[nloc][mloc] = v;
        }
    }
    __syncthreads();

    // transposed write: out[b][n0+nloc][nb+mloc], 64B-contiguous per 4 lanes
    const int bidx = m0 >> 11;          // m0 / 2048
    const int nb = m0 & 2047;           // within-batch position
    const int nloc = tid >> 2;
    const int l4 = tid & 3;
    float* orow = out + (size_t)bidx * kC * kN + (size_t)(n0 + nloc) * kN + nb;
    #pragma unroll
    for (int i = 0; i < 4; i++) {
        const int mloc = l4 * 4 + i * 16;
        float4v v4;
        v4[0] = T[nloc][mloc];     v4[1] = T[nloc][mloc + 1];
        v4[2] = T[nloc][mloc + 2]; v4[3] = T[nloc][mloc + 3];
        *(float4v*)&orow[mloc] = v4;
    }
}

// ---------------------------------------------------------------------------
// 3) LayerNorm, wave-per-row (R14-verified): shuffle-only, 4 rows/block.
//    Rows >= wlim skip the dead f32 writeback.
// ---------------------------------------------------------------------------
__global__ __launch_bounds__(256) void ln_kernel(
    float* __restrict__ x, short* __restrict__ xbf,
    const float* __restrict__ g, const float* __restrict__ bb, int wlim)
{
    const int lane = threadIdx.x & 63;
    const size_t row = (size_t)blockIdx.x * 4 + (threadIdx.x >> 6);

    float4v v = *(const float4v*)&x[row * kC + lane * 4];
    float s = (v[0] + v[1]) + (v[2] + v[3]);
    #pragma unroll
    for (int off = 32; off; off >>= 1) s += __shfl_xor(s, off, 64);
    const float mean = s * (1.0f / kC);

    float d0 = v[0] - mean, d1 = v[1] - mean, d2 = v[2] - mean, d3 = v[3] - mean;
    float s2 = (d0 * d0 + d1 * d1) + (d2 * d2 + d3 * d3);
    #pragma unroll
    for (int off = 32; off; off >>= 1) s2 += __shfl_xor(s2, off, 64);
    const float var = s2 * (1.0f / kC);
    const float r = 1.0f / sqrtf(var + 1e-5f);

    const float4v g4 = *(const float4v*)&g[lane * 4];
    const float4v b4 = *(const float4v*)&bb[lane * 4];
    float4v o;
    o[0] = d0 * r * g4[0] + b4[0];
    o[1] = d1 * r * g4[1] + b4[1];
    o[2] = d2 * r * g4[2] + b4[2];
    o[3] = d3 * r * g4[3] + b4[3];

    if ((int)row < wlim) *(float4v*)&x[row * kC + lane * 4] = o;
    short4v ob;
    ob[0] = f2b(o[0]); ob[1] = f2b(o[1]); ob[2] = f2b(o[2]); ob[3] = f2b(o[3]);
    *(short4v*)&xbf[row * kC + lane * 4] = ob;
}

// ---------------------------------------------------------------------------
// 4) wave-per-query KNN, tournament-tree selection — R6 version verbatim
//    (empirically fastest: 53 us; R7/R8/R15 restructures all regressed).
// ---------------------------------------------------------------------------
#define KNN_RESCAN(CH, BM, BI)                                        \
    do {                                                              \
        float nb_ = 1e30f; int ni_ = kN;                              \
        _Pragma("unroll")                                             \
        for (int c8_ = 0; c8_ < 8; c8_++) {                           \
            int c_ = (CH) * 8 + c8_;                                  \
            float dd_ = (mask & (1u << c_)) ? 1e30f : cd[c_];         \
            if (dd_ < nb_) { nb_ = dd_; ni_ = c_ * 64 + lane; }       \
        }                                                             \
        BM = nb_; BI = ni_;                                           \
    } while (0)

__global__ __launch_bounds__(512) void knn_kernel(
    const float* __restrict__ pos,
    const float* __restrict__ Wr1, const float* __restrict__ br1,
    const float* __restrict__ Wr2, const float* __restrict__ br2,
    int* __restrict__ idx_out, float* __restrict__ bias_out)
{
    __shared__ float px[kN], py[kN], pz[kN];
    __shared__ int selS[8][kKNN];

    const int b = blockIdx.y;
    const int t = threadIdx.x;
    const int lane = t & 63, wv = t >> 6;
    const int n = blockIdx.x * 8 + wv;

    const float* pb = pos + (size_t)b * 3 * kN;
    for (int m = t; m < kN; m += 512) {
        px[m] = pb[m]; py[m] = pb[kN + m]; pz[m] = pb[2 * kN + m];
    }
    __syncthreads();

    const float qx = px[n], qy = py[n], qz = pz[n];
    const float qsq = __fadd_rn(__fadd_rn(__fmul_rn(qx, qx), __fmul_rn(qy, qy)),
                                __fmul_rn(qz, qz));

    float cd[32];
    float bm0 = 1e30f, bm1 = 1e30f, bm2 = 1e30f, bm3 = 1e30f;
    int bi0 = kN, bi1 = kN, bi2 = kN, bi3 = kN;
    #pragma unroll
    for (int c8 = 0; c8 < 8; c8++) {
        {
            const int c = c8, m = c * 64 + lane;
            float ax = px[m], ay = py[m], az = pz[m];
            float asq = __fadd_rn(__fadd_rn(__fmul_rn(ax, ax), __fmul_rn(ay, ay)), __fmul_rn(az, az));
            float dot = __fadd_rn(__fadd_rn(__fmul_rn(qx, ax), __fmul_rn(qy, ay)), __fmul_rn(qz, az));
            float d = __fsub_rn(__fadd_rn(qsq, asq), __fmul_rn(2.0f, dot));
            cd[c] = d;
            if (d < bm0) { bm0 = d; bi0 = m; }
        }
        {
            const int c = c8 + 8, m = c * 64 + lane;
            float ax = px[m], ay = py[m], az = pz[m];
            float asq = __fadd_rn(__fadd_rn(__fmul_rn(ax, ax), __fmul_rn(ay, ay)), __fmul_rn(az, az));
            float dot = __fadd_rn(__fadd_rn(__fmul_rn(qx, ax), __fmul_rn(qy, ay)), __fmul_rn(qz, az));
            float d = __fsub_rn(__fadd_rn(qsq, asq), __fmul_rn(2.0f, dot));
            cd[c] = d;
            if (d < bm1) { bm1 = d; bi1 = m; }
        }
        {
            const int c = c8 + 16, m = c * 64 + lane;
            float ax = px[m], ay = py[m], az = pz[m];
            float asq = __fadd_rn(__fadd_rn(__fmul_rn(ax, ax), __fmul_rn(ay, ay)), __fmul_rn(az, az));
            float dot = __fadd_rn(__fadd_rn(__fmul_rn(qx, ax), __fmul_rn(qy, ay)), __fmul_rn(qz, az));
            float d = __fsub_rn(__fadd_rn(qsq, asq), __fmul_rn(2.0f, dot));
            cd[c] = d;
            if (d < bm2) { bm2 = d; bi2 = m; }
        }
        {
            const int c = c8 + 24, m = c * 64 + lane;
            float ax = px[m], ay = py[m], az = pz[m];
            float asq = __fadd_rn(__fadd_rn(__fmul_rn(ax, ax), __fmul_rn(ay, ay)), __fmul_rn(az, az));
            float dot = __fadd_rn(__fadd_rn(__fmul_rn(qx, ax), __fmul_rn(qy, ay)), __fmul_rn(qz, az));
            float d = __fsub_rn(__fadd_rn(qsq, asq), __fmul_rn(2.0f, dot));
            cd[c] = d;
            if (d < bm3) { bm3 = d; bi3 = m; }
        }
    }

    unsigned mask = 0;
    for (int r = 0; r < kKNN; r++) {
        float best = bm0; int bid = bi0;
        if (bm1 < best) { best = bm1; bid = bi1; }
        if (bm2 < best) { best = bm2; bid = bi2; }
        if (bm3 < best) { best = bm3; bid = bi3; }

        #pragma unroll
        for (int off = 1; off < 64; off <<= 1) {
            float od = __shfl_xor(best, off, 64);
            int   oi = __shfl_xor(bid, off, 64);
            if (od < best || (od == best && oi < bid)) { best = od; bid = oi; }
        }
        if (lane == 0) selS[wv][r] = bid;
        if ((bid & 63) == lane) mask |= 1u << (bid >> 6);

        if (r < kKNN - 1) {
            const int sch = __builtin_amdgcn_readfirstlane(bid >> 9);
            switch (sch) {
                case 0:  KNN_RESCAN(0, bm0, bi0); break;
                case 1:  KNN_RESCAN(1, bm1, bi1); break;
                case 2:  KNN_RESCAN(2, bm2, bi2); break;
                default: KNN_RESCAN(3, bm3, bi3); break;
            }
        }
    }

    const int k = lane >> 2;
    const int part = lane & 3;
    const int m = selS[wv][k];
    const float rx = qx - px[m], ry = qy - py[m], rz = qz - pz[m];
    float partial = 0.0f;
    #pragma unroll
    for (int jj = 0; jj < 16; jj++) {
        int o = part * 16 + jj;
        float h = rx * Wr1[o * 3 + 0] + ry * Wr1[o * 3 + 1] +
                  rz * Wr1[o * 3 + 2] + br1[o];
        partial += gelu_erf(h) * Wr2[o];
    }
    partial += __shfl_xor(partial, 1, 64);
    partial += __shfl_xor(partial, 2, 64);
    if (part == 0) {
        size_t o = ((size_t)b * kN + n) * kKNN + k;
        idx_out[o] = m;
        bias_out[o] = partial + br2[0];
    }
}

// ---------------------------------------------------------------------------
// 5) sparse attention, wave-parallel QK (R17-verified).
// ---------------------------------------------------------------------------
__global__ __launch_bounds__(256) void attn_kernel(
    const float* __restrict__ q, const float* __restrict__ kv,
    const int* __restrict__ idx, const float* __restrict__ bias,
    short* __restrict__ obf)
{
    const int n = blockIdx.x;
    const int b = blockIdx.y;
    const int t = threadIdx.x;
    const int h = t >> 6;
    const int lane = t & 63;

    const size_t row = (size_t)b * kN + n;

    __shared__ int   sidx[kKNN];
    __shared__ float sb[kKNN];
    if (t < kKNN) { sidx[t] = idx[row * kKNN + t]; sb[t] = bias[row * kKNN + t]; }
    __syncthreads();

    // QK: group (j = lane>>2) x chunk (part = lane&3, dims part*16..+15)
    const int j = lane >> 2;
    const int part = lane & 3;
    const size_t krj = (size_t)b * kN + sidx[j];
    const float4v* q4 = (const float4v*)&q[row * kC + h * kDH + part * 16];
    const float4v* k4 = (const float4v*)&kv[krj * 512 + h * kDH + part * 16];
    float partial = 0.0f;
    #pragma unroll
    for (int e = 0; e < 4; e++) {
        float4v qa = q4[e], ka = k4[e];
        partial += qa[0] * ka[0] + qa[1] * ka[1] + qa[2] * ka[2] + qa[3] * ka[3];
    }
    partial += __shfl_xor(partial, 1, 64);
    partial += __shfl_xor(partial, 2, 64);
    const float scj = partial * 0.125f + sb[j];

    // broadcast all 16 scores to every lane (independent shuffles)
    float sc[kKNN];
    #pragma unroll
    for (int jj = 0; jj < kKNN; jj++) sc[jj] = __shfl(scj, jj * 4, 64);

    float mx = sc[0];
    #pragma unroll
    for (int jj = 1; jj < kKNN; jj++) mx = fmaxf(mx, sc[jj]);
    float den = 0.0f;
    #pragma unroll
    for (int jj = 0; jj < kKNN; jj++) { sc[jj] = expf(sc[jj] - mx); den += sc[jj]; }
    const float inv = 1.0f / den;

    // PV: lane = d (unchanged expressions and j-order)
    const int d = lane;
    float o = 0.0f;
    #pragma unroll
    for (int jj = 0; jj < kKNN; jj++) {
        size_t kr = (size_t)b * kN + sidx[jj];
        o += sc[jj] * inv * kv[kr * 512 + kC + h * kDH + d];
    }
    obf[row * kC + h * kDH + d] = f2b(o);
}

// ---------------------------------------------------------------------------
extern "C" void kernel_launch(void* const* d_in, const int* in_sizes, int n_in,
                              void* d_out, int out_size, void* d_ws, size_t ws_size,
                              hipStream_t stream)
{
    const float* src1 = (const float*)d_in[0];
    const float* src2 = (const float*)d_in[1];
    const float* pos  = (const float*)d_in[2];
    const float* Wp   = (const float*)d_in[3];
    const float* bp   = (const float*)d_in[4];
    const float* Wr1  = (const float*)d_in[5];
    const float* br1  = (const float*)d_in[6];
    const float* Wr2  = (const float*)d_in[7];
    const float* br2  = (const float*)d_in[8];
    const float* Wqkv = (const float*)d_in[9];
    const float* bqkv = (const float*)d_in[10];
    const float* Wo   = (const float*)d_in[11];
    const float* bo   = (const float*)d_in[12];
    const float* g13  = (const float*)d_in[13];
    const float* b13  = (const float*)d_in[14];
    const float* g12  = (const float*)d_in[15];
    const float* b12  = (const float*)d_in[16];
    const float* W1   = (const float*)d_in[17];
    const float* b1   = (const float*)d_in[18];
    const float* W2   = (const float*)d_in[19];
    const float* b2   = (const float*)d_in[20];
    float* out = (float*)d_out;                      // fp32 output (b,c,n)

    const size_t S = (size_t)kB * kN * kC;  // 2,097,152 floats
    float* ws = (float*)d_ws;
    // f32 buffers
    float* x1  = ws;             // proj s1 out; LN13 in place; resid for out-proj
    float* s2  = ws + S;         // proj s2 out (contiguous after x1)
    float* qb  = ws + 2 * S;     // q f32; yb aliases after attn
    float* kvb = ws + 3 * S;     // fused k|v f32, row stride 512 (2S); hbf aliases
    float* yb  = ws + 2 * S;     // alias qb (dead after attn)
    // bf16x2 staging for proj (dead after proj_mfma; alias qb/kvb region)
    short* srcThi = (short*)(ws + 2 * S);            // 16384x256 shorts = [2S,3S)
    short* srcTlo = (short*)(ws + 3 * S);            // 16384x256 shorts = [3S,4S)
    // bf16 buffers (as shorts)
    short* x1bf = (short*)(ws + 5 * S);              // S shorts  [5S, 5.5S)
    short* x2bf = (short*)(ws + 5 * S) + S;          // S shorts  [5.5S, 6S)
    short* ybf  = (short*)(ws + 6 * S);              // S shorts  [6S, 6.5S)
    short* obf  = (short*)(ws + 6 * S) + S;          // S shorts  [6.5S, 7S)
    short* hbf  = (short*)(ws + 3 * S);              // alias kvb: 4S shorts (M x DFF)
    // knn outputs
    int*   idxb  = (int*)(ws + 7 * S);
    float* biasb = ws + 7 * S + (size_t)kB * kN * kKNN;
    // bf16 weights (contiguous): [qkv][o][w1][w2][wp_hi][wp_lo]
    short* wbf    = (short*)(ws + 7 * S + 2 * (size_t)kB * kN * kKNN);
    short* Wqkvbf = wbf;                  // 196608 shorts
    short* Wobf   = wbf + 196608;         // 65536
    short* W1bf   = wbf + 262144;         // 262144
    short* W2bf   = wbf + 524288;         // 262144
    short* Wphi   = wbf + 786432;         // 65536
    short* Wplo   = wbf + 851968;         // 65536

    const int M = kB * kN;  // 8192

    // 0) all weight conversions in one launch
    cvt_all<<<416, 256, 0, stream>>>(Wqkv, Wo, W1, W2, Wp, wbf);

    // 1) input projection: transpose+split src, then bf16x3 MFMA GEMM (BK=64)
    transpose_cvt<<<dim3(kN / 32, kC / 32, 8), dim3(32, 8), 0, stream>>>(
        src1, src2, srcThi, srcTlo);
    proj_mfma<<<dim3(kC / 64, 2 * M / 64), 256, 0, stream>>>(
        srcThi, srcTlo, Wphi, Wplo, bp, x1);   // writes x1 then s2 (contiguous)

    // 2) LN13: 16384 rows, wave-per-row; f32 writeback only for x1 half
    ln_kernel<<<2 * M / 4, 256, 0, stream>>>(x1, x1bf, g13, b13, M);

    // 3) KNN + rel-pos bias (R6 config: 8 queries/block, 512 threads)
    knn_kernel<<<dim3(kN / 8, kB), 512, 0, stream>>>(pos, Wr1, br1, Wr2, br2, idxb, biasb);

    // 4) merged q + kv projection (64x64 tiles, BK=64, gload_lds)
    qkv_gemm<<<dim3(12, M / 64), 256, 0, stream>>>(x1bf, x2bf, Wqkvbf, bqkv, qb, kvb);

    // 5) sparse attention (wave-parallel QK, bf16 out)
    attn_kernel<<<dim3(kN, kB), 256, 0, stream>>>(qb, kvb, idxb, biasb, obf);

    // 6) out-proj + residual(x1), then LN12
    mfma_gemm_bf<<<dim3(kC / 64, M / 64), 256, 0, stream>>>(
        obf, Wobf, bo, x1, yb, nullptr, M, kC, kC, 0);
    ln_kernel<<<M / 4, 256, 0, stream>>>(yb, ybf, g12, b12, M);

    // 7) FFN: ffn1 bf16-only out; ffn2 fused transposed write to final out
    mfma_gemm_bf<<<dim3(kDFF / 64, M / 64), 256, 0, stream>>>(
        ybf, W1bf, b1, nullptr, nullptr, hbf, M, kDFF, kC, 1);
    ffn2_gemm_tr<<<dim3(kC / 64, M / 64), 256, 0, stream>>>(
        hbf, W2bf, b2, yb, out);
}